// Round 3
// baseline (547.201 us; speedup 1.0000x reference)
//
#include <hip/hip_runtime.h>
#include <cstdint>

#define N 8192
#define FIN 256
#define FOUT 128
#define ALPHA 0.2f
#define KS 8                 // global j-slices (one per wave)
#define JSL (N / KS)         // 1024 j's per wave
#define NSTEP (JSL / 32)     // 32 k-steps of 32 j's

typedef unsigned short u16;
typedef __attribute__((ext_vector_type(8))) short short8;
typedef __attribute__((ext_vector_type(4))) float floatx4;

__device__ __forceinline__ u16 bf16_rne(float f) {
  uint32_t u = __float_as_uint(f);
  u += 0x7fff + ((u >> 16) & 1);
  return (u16)(u >> 16);
}

// ---------------------------------------------------------------------------
// Kernel 1: h = x@W (fp32); write hT3 (bf16, tiled [jb][m][q][nt][8] so k_gat
// b-frags are 8 imm-offset loads off one pointer); src = h@a1, dst = h@a2.
// 1024 blocks x 256 thr, 8 rows/block (4 blocks/CU for latency hiding).
// W loads prefetched distance-2 in registers.
// ---------------------------------------------------------------------------
__global__ __launch_bounds__(256) void k_proj(const float* __restrict__ x,
                                              const float* __restrict__ W,
                                              const float* __restrict__ a,
                                              u16* __restrict__ hT3,
                                              float* __restrict__ srcv,
                                              float* __restrict__ dstv) {
  __shared__ float xs[8 * FIN];                     // 8 KB
  __shared__ float partS[4][4], partD[4][4];
  const int t = threadIdx.x;
  const int R0 = blockIdx.x * 8;

  const float4* xv = (const float4*)(x + (size_t)R0 * FIN);
  float4* xsv = (float4*)xs;
  xsv[t] = xv[t];
  xsv[t + 256] = xv[t + 256];
  __syncthreads();

  const int c  = t & 127;           // output column
  const int rg = (t >> 7) * 4;      // row group base (wave-uniform)

  float acc[4] = {0.f, 0.f, 0.f, 0.f};
  float wa[4], wb[4];
  #pragma unroll
  for (int j = 0; j < 4; ++j) wa[j] = W[j * FOUT + c];
  #pragma unroll
  for (int j = 0; j < 4; ++j) wb[j] = W[(4 + j) * FOUT + c];

  for (int k4 = 0; k4 < FIN / 4; ++k4) {
    float wc[4];
    #pragma unroll
    for (int j = 0; j < 4; ++j) { wc[j] = wa[j]; wa[j] = wb[j]; }
    const int kn = (k4 + 2 < FIN / 4) ? k4 + 2 : k4;
    #pragma unroll
    for (int j = 0; j < 4; ++j) wb[j] = W[(kn * 4 + j) * FOUT + c];
    #pragma unroll
    for (int i = 0; i < 4; ++i) {
      const float4 xq = *(const float4*)&xs[(rg + i) * FIN + k4 * 4];
      acc[i] += xq.x * wc[0] + xq.y * wc[1] + xq.z * wc[2] + xq.w * wc[3];
    }
  }

  // store to hT3: col c -> (m = c&15, nt = c>>4); rows R0+rg..+4 are 4
  // consecutive j's starting at a multiple of 4 (never crosses a q-octet).
  {
    const int j = R0 + rg;
    const int jb = j >> 5, q = (j >> 3) & 3, jj = j & 7;
    const int m = c & 15, nt = c >> 4;
    union { u16 u[4]; uint2 v; } pk;
    #pragma unroll
    for (int i = 0; i < 4; ++i) pk.u[i] = bf16_rne(acc[i]);
    *(uint2*)(hT3 + (size_t)(((jb * 16 + m) * 4 + q) * 8 + nt) * 8 + jj) = pk.v;
  }

  // src/dst row reductions
  const float a1 = a[c], a2 = a[FOUT + c];
  float s4[4], d4[4];
  #pragma unroll
  for (int i = 0; i < 4; ++i) { s4[i] = acc[i] * a1; d4[i] = acc[i] * a2; }
  #pragma unroll
  for (int off = 32; off > 0; off >>= 1) {
    #pragma unroll
    for (int i = 0; i < 4; ++i) {
      s4[i] += __shfl_down(s4[i], off);
      d4[i] += __shfl_down(d4[i], off);
    }
  }
  const int wv = t >> 6, lane = t & 63;
  if (lane == 0) {
    #pragma unroll
    for (int i = 0; i < 4; ++i) { partS[wv][i] = s4[i]; partD[wv][i] = d4[i]; }
  }
  __syncthreads();
  if (t < 16) {
    const int i = t & 3, rg2 = (t >> 2) & 1, which = t >> 3;
    if (which == 0) srcv[R0 + rg2 * 4 + i] = partS[rg2*2][i] + partS[rg2*2+1][i];
    else            dstv[R0 + rg2 * 4 + i] = partD[rg2*2][i] + partD[rg2*2+1][i];
  }
}

// ---------------------------------------------------------------------------
// Kernel 2: fused masked-softmax attention, wave-independent (NO barriers or
// LDS in the main loop). Each wave owns 16 rows x 128 cols over a 1024-j
// slice: lane(q,m) computes p[row m][j0+q*8..+8] in registers (exactly the
// MFMA A-frag layout), feeds 8 MFMAs per 32-j step. adj prefetched
// distance-2; b-frags off one pointer (hT3 tiled), L1-shared between the two
// waves on the same j-slice. One barrier at the end pair-reduces j-halves.
// blockIdx = bm(0..255 strip-pair) | jp<<8 (0..3). 1024 blocks.
// ---------------------------------------------------------------------------
__global__ __launch_bounds__(256, 4) void k_gat(const int* __restrict__ adj,
                                                const u16* __restrict__ hT3,
                                                const float* __restrict__ srcv,
                                                const float* __restrict__ dstv,
                                                float* __restrict__ P,
                                                float* __restrict__ lp) {
  __shared__ float redP[2][16 * FOUT];    // 16 KB
  __shared__ float redL[2][16];
  const int t = threadIdx.x;
  const int wv = t >> 6, lane = t & 63;
  const int q = lane >> 4, m = lane & 15;
  const int bm = blockIdx.x & 255;
  const int jp = blockIdx.x >> 8;         // 0..3 (stored partial index)
  const int sp = wv >> 1;                 // strip within pair
  const int jh = wv & 1;                  // j-half within pair
  const int strip = bm * 2 + sp;
  const int R0 = strip * 16;
  const int ks8 = jp * 2 + jh;            // global slice 0..7
  const int j0 = ks8 * JSL;

  const float srcm = srcv[R0 + m];
  const int*   adjp = adj + (size_t)(R0 + m) * N + j0 + q * 8;
  const float* dstp = dstv + j0 + q * 8;
  const u16*   hp   = hT3 + (size_t)(j0 >> 5) * 4096 + (m * 4 + q) * 64;

  floatx4 acc[8];
  #pragma unroll
  for (int nt = 0; nt < 8; ++nt) acc[nt] = (floatx4){0.f, 0.f, 0.f, 0.f};
  float lsum = 0.f;

  int4 abuf[2][2];
  abuf[0][0] = *(const int4*)(adjp);
  abuf[0][1] = *(const int4*)(adjp + 4);
  abuf[1][0] = *(const int4*)(adjp + 32);
  abuf[1][1] = *(const int4*)(adjp + 36);

  for (int i = 0; i < NSTEP; ++i) {
    // b-frags for this step: 8 x 16B, one pointer + imm offsets
    const u16* hpi = hp + (size_t)i * 4096;
    short8 bf[8];
    #pragma unroll
    for (int nt = 0; nt < 8; ++nt) bf[nt] = *(const short8*)(hpi + nt * 8);
    const float4 d0 = *(const float4*)(dstp + i * 32);
    const float4 d1 = *(const float4*)(dstp + i * 32 + 4);

    const int4 A0 = abuf[i & 1][0];
    const int4 A1 = abuf[i & 1][1];
    // prefetch adj for step i+2 (distance-2: ~2 iterations of cover)
    const int inx = (i + 2 < NSTEP) ? i + 2 : i;
    abuf[i & 1][0] = *(const int4*)(adjp + inx * 32);
    abuf[i & 1][1] = *(const int4*)(adjp + inx * 32 + 4);

    const int   ai[8] = {A0.x, A0.y, A0.z, A0.w, A1.x, A1.y, A1.z, A1.w};
    const float df[8] = {d0.x, d0.y, d0.z, d0.w, d1.x, d1.y, d1.z, d1.w};
    union { u16 u[8]; short8 s; } pk;
    #pragma unroll
    for (int e = 0; e < 8; ++e) {
      float v = srcm + df[e];
      v = v > 0.f ? v : ALPHA * v;
      const float p = ai[e] > 0 ? __expf(v) : 0.f;
      lsum += p;
      pk.u[e] = bf16_rne(p);
    }
    #pragma unroll
    for (int nt = 0; nt < 8; ++nt)
      acc[nt] = __builtin_amdgcn_mfma_f32_16x16x32_bf16(pk.s, bf[nt], acc[nt], 0, 0, 0);
  }

  // row-sum: reduce over the 4 q-lanes sharing row m
  lsum += __shfl_xor(lsum, 16);
  lsum += __shfl_xor(lsum, 32);

  // pair-reduce the two j-halves (waves {0,1} -> strip sp=0, {2,3} -> sp=1)
  if (jh == 1) {
    float* rp = redP[sp];
    #pragma unroll
    for (int nt = 0; nt < 8; ++nt)
      #pragma unroll
      for (int ri = 0; ri < 4; ++ri)
        rp[(q * 4 + ri) * FOUT + nt * 16 + m] = acc[nt][ri];
    if (lane < 16) redL[sp][lane] = lsum;
  }
  __syncthreads();
  if (jh == 0) {
    const float* rp = redP[sp];
    float* Pp = P + ((size_t)jp * N + R0) * FOUT;
    #pragma unroll
    for (int nt = 0; nt < 8; ++nt)
      #pragma unroll
      for (int ri = 0; ri < 4; ++ri) {
        const int idx = (q * 4 + ri) * FOUT + nt * 16 + m;
        Pp[idx] = acc[nt][ri] + rp[idx];
      }
    if (lane < 16) lp[(size_t)jp * N + R0 + lane] = lsum + redL[sp][lane];
  }
}

// ---------------------------------------------------------------------------
// Kernel 3: sum 4 partials, normalize by row-sum. ~20 MB traffic.
// ---------------------------------------------------------------------------
__global__ __launch_bounds__(256) void k_norm(const float* __restrict__ P,
                                              const float* __restrict__ lp,
                                              float* __restrict__ out) {
  const int idx = blockIdx.x * 256 + threadIdx.x;   // 0 .. N*FOUT/4-1
  const int rr = idx >> 5;
  const int c4 = (idx & 31) * 4;
  const float l = lp[rr] + lp[N + rr] + lp[2 * N + rr] + lp[3 * N + rr];
  const float inv = 1.0f / l;
  float4 s = {0.f, 0.f, 0.f, 0.f};
  #pragma unroll
  for (int jp = 0; jp < 4; ++jp) {
    const float4 p = *(const float4*)(P + ((size_t)jp * N + rr) * FOUT + c4);
    s.x += p.x; s.y += p.y; s.z += p.z; s.w += p.w;
  }
  s.x *= inv; s.y *= inv; s.z *= inv; s.w *= inv;
  *(float4*)(out + (size_t)rr * FOUT + c4) = s;
}

extern "C" void kernel_launch(void* const* d_in, const int* in_sizes, int n_in,
                              void* d_out, int out_size, void* d_ws, size_t ws_size,
                              hipStream_t stream) {
  const float* x   = (const float*)d_in[0];
  const int*   adj = (const int*)d_in[1];
  const float* W   = (const float*)d_in[2];
  const float* a   = (const float*)d_in[3];
  float* out = (float*)d_out;

  char* ws = (char*)d_ws;
  u16*   hT3  = (u16*)ws;     ws += (size_t)FOUT * N * sizeof(u16);            // 2 MB
  float* srcv = (float*)ws;   ws += (size_t)N * sizeof(float);
  float* dstv = (float*)ws;   ws += (size_t)N * sizeof(float);
  float* P    = (float*)ws;   ws += (size_t)4 * N * FOUT * sizeof(float);      // 16 MB
  float* lp   = (float*)ws;   ws += (size_t)4 * N * sizeof(float);

  k_proj<<<N / 8, 256, 0, stream>>>(x, W, a, hT3, srcv, dstv);
  k_gat <<<1024, 256, 0, stream>>>(adj, hT3, srcv, dstv, P, lp);
  k_norm<<<(N * FOUT / 4) / 256, 256, 0, stream>>>(P, lp, out);
}